// Round 1
// baseline (2215.040 us; speedup 1.0000x reference)
//
#include <hip/hip_runtime.h>

#define T 1024
#define BATCH 512
#define EMB 64
#define HID 64
#define NGATE 256   // 4*HID

__device__ __forceinline__ float fast_sigmoid(float x) {
    return 1.0f / (1.0f + __expf(-x));
}
__device__ __forceinline__ float fast_tanh(float x) {
    // tanh(x) = 1 - 2/(exp(2x)+1); saturates correctly at +/-1
    return 1.0f - 2.0f / (__expf(2.0f * x) + 1.0f);
}

// One block per (batch elem, direction). 256 threads; thread j owns gate
// column j with W[:,j], U[:,j] in registers (128 VGPRs). h, x broadcast via LDS.
__global__ __launch_bounds__(256, 3)
void lstm_kernel(const int* __restrict__ x,
                 const float* __restrict__ emb,
                 const float* __restrict__ Wf, const float* __restrict__ Uf,
                 const float* __restrict__ bf,
                 const float* __restrict__ Wb, const float* __restrict__ Ub,
                 const float* __restrict__ bb,
                 float* __restrict__ hcat)   // [BATCH][2*HID]
{
    const int tid = threadIdx.x;       // 0..255 gate column
    const int bidx = blockIdx.x;       // 0..1023
    const int b = bidx >> 1;
    const int d = bidx & 1;            // 0 = fwd, 1 = bwd

    const float* W    = d ? Wb : Wf;
    const float* U    = d ? Ub : Uf;
    const float* bias = d ? bb : bf;

    // Column-resident weights: W[k][tid], U[k][tid]  (row-major [64][256])
    float wreg[EMB];
    float ureg[HID];
#pragma unroll
    for (int k = 0; k < EMB; ++k) wreg[k] = W[k * NGATE + tid];
#pragma unroll
    for (int k = 0; k < HID; ++k) ureg[k] = U[k * NGATE + tid];
    const float bj = bias[tid];

    __shared__ float xs[EMB];
    __shared__ float hs[HID];
    __shared__ float zs[NGATE];

    float creg = 0.0f;   // owned by tid < HID
    float hreg = 0.0f;
    if (tid < HID) hs[tid] = 0.0f;
    __syncthreads();

    const int* xrow = x + b * T;

    for (int s = 0; s < T; ++s) {
        const int t = d ? (T - 1 - s) : s;
        const int token = xrow[t];                 // uniform -> scalar load
        if (tid < EMB) xs[tid] = emb[token * EMB + tid];
        __syncthreads();

        // z = x.W[:,j] + h.U[:,j] + b[j], 4 partial chains for ILP
        float z0 = 0.f, z1 = 0.f, z2 = 0.f, z3 = 0.f;
#pragma unroll
        for (int k = 0; k < EMB; k += 4) {
            z0 += xs[k + 0] * wreg[k + 0];
            z1 += xs[k + 1] * wreg[k + 1];
            z2 += xs[k + 2] * wreg[k + 2];
            z3 += xs[k + 3] * wreg[k + 3];
        }
#pragma unroll
        for (int k = 0; k < HID; k += 4) {
            z0 += hs[k + 0] * ureg[k + 0];
            z1 += hs[k + 1] * ureg[k + 1];
            z2 += hs[k + 2] * ureg[k + 2];
            z3 += hs[k + 3] * ureg[k + 3];
        }
        const float z = ((z0 + z1) + (z2 + z3)) + bj;

        // gate layout: [i 0:64 | f 64:128 | g 128:192 | o 192:256]
        const float a = (tid < 128 || tid >= 192) ? fast_sigmoid(z)
                                                  : fast_tanh(z);
        zs[tid] = a;
        __syncthreads();

        if (tid < HID) {
            const float ig = zs[tid];
            const float fg = zs[HID + tid];
            const float gg = zs[2 * HID + tid];
            const float og = zs[3 * HID + tid];
            const float cn = fg * creg + ig * gg;
            const float hn = og * fast_tanh(cn);
            if (token != 0) { creg = cn; hreg = hn; }   // mask: keep old if pad
            hs[tid] = hreg;
        }
        // no 3rd barrier needed: hs readers pass through next iter's barrier
        // before reading; zs re-writers pass through it before writing.
    }

    if (tid < HID) hcat[b * (2 * HID) + d * HID + tid] = hreg;
}

// Tiny MLP head: out[b] = relu(hcat[b] @ W1 + b1) @ W2 + b2
__global__ void mlp_kernel(const float* __restrict__ hcat,
                           const float* __restrict__ W1, const float* __restrict__ b1,
                           const float* __restrict__ W2, const float* __restrict__ b2,
                           float* __restrict__ out)
{
    const int b = blockIdx.x;
    const int tid = threadIdx.x;  // 64 threads
    __shared__ float h1[32];
    const float* h = hcat + b * (2 * HID);
    if (tid < 32) {
        float acc = b1[tid];
#pragma unroll
        for (int k = 0; k < 2 * HID; ++k) acc += h[k] * W1[k * 32 + tid];
        h1[tid] = fmaxf(acc, 0.0f);
    }
    __syncthreads();
    if (tid == 0) {
        float acc = b2[0];
#pragma unroll
        for (int m = 0; m < 32; ++m) acc += h1[m] * W2[m];
        out[b] = acc;
    }
}

extern "C" void kernel_launch(void* const* d_in, const int* in_sizes, int n_in,
                              void* d_out, int out_size, void* d_ws, size_t ws_size,
                              hipStream_t stream)
{
    const int*   x   = (const int*)d_in[0];
    const float* emb = (const float*)d_in[1];
    const float* Wf  = (const float*)d_in[2];
    const float* Uf  = (const float*)d_in[3];
    const float* bf  = (const float*)d_in[4];
    const float* Wb  = (const float*)d_in[5];
    const float* Ub  = (const float*)d_in[6];
    const float* bb  = (const float*)d_in[7];
    const float* W1  = (const float*)d_in[8];
    const float* b1  = (const float*)d_in[9];
    const float* W2  = (const float*)d_in[10];
    const float* b2  = (const float*)d_in[11];
    float* out  = (float*)d_out;
    float* hcat = (float*)d_ws;   // [512][128] = 256 KB

    lstm_kernel<<<dim3(2 * BATCH), dim3(256), 0, stream>>>(
        x, emb, Wf, Uf, bf, Wb, Ub, bb, hcat);
    mlp_kernel<<<dim3(BATCH), dim3(64), 0, stream>>>(
        hcat, W1, b1, W2, b2, out);
}

// Round 2
// 1562.242 us; speedup vs baseline: 1.4179x; 1.4179x over previous
//
#include <hip/hip_runtime.h>

#define T 1024
#define BATCH 512
#define EMB 64
#define HID 64
#define NGATE 256        // 4*HID
#define VOCABP1 50001

__device__ __forceinline__ float fast_sigmoid(float x) {
    return 1.0f / (1.0f + __expf(-x));
}
__device__ __forceinline__ float fast_tanh(float x) {
    return 1.0f - 2.0f / (__expf(2.0f * x) + 1.0f);
}
__device__ __forceinline__ float bcast(float v, int k) {
    return __int_as_float(__builtin_amdgcn_readlane(__float_as_int(v), k));
}

// ---------------------------------------------------------------------------
// Kernel A: zx_table[d][v][j] = bias[d][j] + sum_k emb[v][k] * W[d][k][j]
// Fully parallel GEMM-like precompute; weights live in registers, emb row is
// broadcast with v_readlane (no LDS).  2048 blocks grid-stride over vocab.
// ---------------------------------------------------------------------------
__global__ __launch_bounds__(256, 3)
void zxtab_kernel(const float* __restrict__ emb,
                  const float* __restrict__ Wf, const float* __restrict__ bf,
                  const float* __restrict__ Wb, const float* __restrict__ bb,
                  float* __restrict__ zf_tab, float* __restrict__ zb_tab)
{
    const int j = threadIdx.x;
    const int lane = j & 63;
    float wf[EMB], wb[EMB];
#pragma unroll
    for (int k = 0; k < EMB; ++k) wf[k] = Wf[k * NGATE + j];
#pragma unroll
    for (int k = 0; k < EMB; ++k) wb[k] = Wb[k * NGATE + j];
    const float bfj = bf[j];
    const float bbj = bb[j];

    for (int r = blockIdx.x; r < VOCABP1; r += gridDim.x) {
        const float ev = emb[r * EMB + lane];   // lane l holds emb[r][l]
        float f0 = bfj, f1 = 0.f, b0 = bbj, b1 = 0.f;
#pragma unroll
        for (int k = 0; k < EMB; k += 2) {
            const float e0 = bcast(ev, k);
            const float e1 = bcast(ev, k + 1);
            f0 = fmaf(e0, wf[k],     f0);
            f1 = fmaf(e1, wf[k + 1], f1);
            b0 = fmaf(e0, wb[k],     b0);
            b1 = fmaf(e1, wb[k + 1], b1);
        }
        zf_tab[r * NGATE + j] = f0 + f1;
        zb_tab[r * NGATE + j] = b0 + b1;
    }
}

// ---------------------------------------------------------------------------
// Kernel B: recurrence only.  One block per (batch, dir); thread j owns gate
// column j with U[:,j] in registers.  h,c replicated one-per-lane in every
// wave; h broadcast via v_readlane (VALU pipe, no LDS).  Cross-wave exchange
// of the 4 activated gate values via double-buffered LDS, ONE barrier/step.
// x@W arrives as a prefetched coalesced row of the precomputed table.
// ---------------------------------------------------------------------------
__global__ __launch_bounds__(256, 4)
void lstm_kernel(const int* __restrict__ x,
                 const float* __restrict__ Uf, const float* __restrict__ Ub,
                 const float* __restrict__ zf_tab,
                 const float* __restrict__ zb_tab,
                 float* __restrict__ hcat)    // [BATCH][2*HID]
{
    const int tid  = threadIdx.x;
    const int lane = tid & 63;
    const int wid  = tid >> 6;        // 0:i 1:f 2:g 3:o
    const int b    = blockIdx.x >> 1;
    const int d    = blockIdx.x & 1;

    const float* U    = d ? Ub : Uf;
    const float* ztab = d ? zb_tab : zf_tab;

    float ureg[HID];
#pragma unroll
    for (int k = 0; k < HID; ++k) ureg[k] = U[k * NGATE + tid];

    __shared__ float zs[2][NGATE];

    float hval = 0.0f;   // lane l of every wave: h[l]
    float cval = 0.0f;

    const int* xrow = x + b * T;

    // software pipeline: token + zx row one step ahead
    int   tok_cur = xrow[d ? (T - 1) : 0];
    float zpre    = ztab[tok_cur * NGATE + tid];

    for (int s = 0; s < T; ++s) {
        const int t  = d ? (T - 1 - s) : s;
        int   tok_next = 0;
        float znext    = 0.0f;
        if (s + 1 < T) {
            tok_next = xrow[d ? (t - 1) : (t + 1)];
            znext    = ztab[tok_next * NGATE + tid];   // in flight during compute
        }

        // z = zx + h . U[:,j]  (4 chains, readlane broadcast of h)
        float z0 = zpre, z1 = 0.f, z2 = 0.f, z3 = 0.f;
#pragma unroll
        for (int k = 0; k < HID; k += 4) {
            z0 = fmaf(bcast(hval, k + 0), ureg[k + 0], z0);
            z1 = fmaf(bcast(hval, k + 1), ureg[k + 1], z1);
            z2 = fmaf(bcast(hval, k + 2), ureg[k + 2], z2);
            z3 = fmaf(bcast(hval, k + 3), ureg[k + 3], z3);
        }
        const float z = (z0 + z1) + (z2 + z3);

        // wave-uniform activation choice: wave 2 = g (tanh), others sigmoid
        const float a = (wid == 2) ? fast_tanh(z) : fast_sigmoid(z);

        float* buf = zs[s & 1];
        buf[tid] = a;
        __syncthreads();                       // the only barrier per step

        // every wave redundantly updates its replica of (h,c) for lane l
        const float ig = buf[lane];
        const float fg = buf[HID + lane];
        const float gg = buf[2 * HID + lane];
        const float og = buf[3 * HID + lane];
        const float cn = fmaf(fg, cval, ig * gg);
        const float hn = og * fast_tanh(cn);
        if (tok_cur != 0) { cval = cn; hval = hn; }   // pad mask (uniform)

        tok_cur = tok_next;
        zpre    = znext;
        // no 2nd barrier: next iter writes zs[(s+1)&1]; a wave can only
        // overwrite zs[s&1] at iter s+2, after passing barrier s+1, which
        // all waves reach only after their reads above.
    }

    if (tid < HID) hcat[b * (2 * HID) + d * HID + tid] = hval;
}

// ---------------------------------------------------------------------------
// Tiny MLP head: out[b] = relu(hcat[b] @ W1 + b1) @ W2 + b2
// ---------------------------------------------------------------------------
__global__ void mlp_kernel(const float* __restrict__ hcat,
                           const float* __restrict__ W1, const float* __restrict__ b1,
                           const float* __restrict__ W2, const float* __restrict__ b2,
                           float* __restrict__ out)
{
    const int b = blockIdx.x;
    const int tid = threadIdx.x;  // 64 threads
    __shared__ float h1[32];
    const float* h = hcat + b * (2 * HID);
    if (tid < 32) {
        float acc = b1[tid];
#pragma unroll
        for (int k = 0; k < 2 * HID; ++k) acc += h[k] * W1[k * 32 + tid];
        h1[tid] = fmaxf(acc, 0.0f);
    }
    __syncthreads();
    if (tid == 0) {
        float acc = b2[0];
#pragma unroll
        for (int m = 0; m < 32; ++m) acc += h1[m] * W2[m];
        out[b] = acc;
    }
}

extern "C" void kernel_launch(void* const* d_in, const int* in_sizes, int n_in,
                              void* d_out, int out_size, void* d_ws, size_t ws_size,
                              hipStream_t stream)
{
    const int*   x   = (const int*)d_in[0];
    const float* emb = (const float*)d_in[1];
    const float* Wf  = (const float*)d_in[2];
    const float* Uf  = (const float*)d_in[3];
    const float* bf  = (const float*)d_in[4];
    const float* Wb  = (const float*)d_in[5];
    const float* Ub  = (const float*)d_in[6];
    const float* bb  = (const float*)d_in[7];
    const float* W1  = (const float*)d_in[8];
    const float* b1  = (const float*)d_in[9];
    const float* W2  = (const float*)d_in[10];
    const float* b2  = (const float*)d_in[11];
    float* out = (float*)d_out;

    // workspace layout: [zf_tab | zb_tab | hcat]
    float* zf_tab = (float*)d_ws;                               // 50001*256 f32
    float* zb_tab = zf_tab + (size_t)VOCABP1 * NGATE;           // 50001*256 f32
    float* hcat   = zb_tab + (size_t)VOCABP1 * NGATE;           // 512*128  f32

    zxtab_kernel<<<dim3(2048), dim3(256), 0, stream>>>(
        emb, Wf, bf, Wb, bb, zf_tab, zb_tab);
    lstm_kernel<<<dim3(2 * BATCH), dim3(256), 0, stream>>>(
        x, Uf, Ub, zf_tab, zb_tab, hcat);
    mlp_kernel<<<dim3(BATCH), dim3(64), 0, stream>>>(
        hcat, W1, b1, W2, b2, out);
}

// Round 4
// 1283.027 us; speedup vs baseline: 1.7264x; 1.2176x over previous
//
#include <hip/hip_runtime.h>

#define T 1024
#define BATCH 512
#define EMB 64
#define HID 64
#define NGATE 256        // 4*HID
#define VOCABP1 50001

__device__ __forceinline__ float fast_sigmoid(float x) {
    return 1.0f / (1.0f + __expf(-x));
}
__device__ __forceinline__ float fast_tanh(float x) {
    return 1.0f - 2.0f / (__expf(2.0f * x) + 1.0f);
}
__device__ __forceinline__ float bcastf(float v, int k) {
    return __int_as_float(__builtin_amdgcn_readlane(__float_as_int(v), k));
}
__device__ __forceinline__ int bcasti(int v, int k) {
    return __builtin_amdgcn_readlane(v, k);
}

// ---------------------------------------------------------------------------
// Kernel A: gate-interleaved zx table.
//   ztab[v][l][g] = bias[g*64+l] + sum_k emb[v][k] * W[k][g*64+l]
// so thread (unit l, wave w) of the LSTM kernel reads its two gates {2w,2w+1}
// as one float2 at offset v*256 + l*4 + 2w.
// ---------------------------------------------------------------------------
__global__ __launch_bounds__(256, 3)
void zxtab_kernel(const float* __restrict__ emb,
                  const float* __restrict__ Wf, const float* __restrict__ bf,
                  const float* __restrict__ Wb, const float* __restrict__ bb,
                  float* __restrict__ zf_tab, float* __restrict__ zb_tab)
{
    const int j    = threadIdx.x;       // output slot: l = j>>2, g = j&3
    const int lane = j & 63;
    const int col  = (j & 3) * 64 + (j >> 2);   // original gate column
    float wf[EMB], wb[EMB];
#pragma unroll
    for (int k = 0; k < EMB; ++k) wf[k] = Wf[k * NGATE + col];
#pragma unroll
    for (int k = 0; k < EMB; ++k) wb[k] = Wb[k * NGATE + col];
    const float bfj = bf[col];
    const float bbj = bb[col];

    for (int r = blockIdx.x; r < VOCABP1; r += gridDim.x) {
        const float ev = emb[r * EMB + lane];   // lane k holds emb[r][k]
        float f0 = bfj, f1 = 0.f, b0 = bbj, b1 = 0.f;
#pragma unroll
        for (int k = 0; k < EMB; k += 2) {
            const float e0 = bcastf(ev, k);
            const float e1 = bcastf(ev, k + 1);
            f0 = fmaf(e0, wf[k],     f0);
            f1 = fmaf(e1, wf[k + 1], f1);
            b0 = fmaf(e0, wb[k],     b0);
            b1 = fmaf(e1, wb[k + 1], b1);
        }
        zf_tab[r * NGATE + j] = f0 + f1;
        zb_tab[r * NGATE + j] = b0 + b1;
    }
}

// ---------------------------------------------------------------------------
// Kernel B: recurrence. One block = one (batch, dir), 128 threads (2 waves).
// lane l = hidden unit; wave 0 owns gates {i,f}, wave 1 owns {g,o}.
// Each thread holds U[:, 2w*64+l] and U[:, (2w+1)*64+l] in 128 VGPRs; one
// readlane broadcast of h[k] feeds two FMAs. Cross-wave exchange = 2 floats
// per thread through double-buffered LDS, ONE barrier/step. zx row is a
// prefetched float2; tokens pre-chunked 64 steps ahead.
// amdgpu_waves_per_eu(2,2): pin exactly 2 waves/SIMD -> 256-VGPR budget, no
// occupancy-heuristic spilling (R2 failure: VGPR_Count=40, weights in AGPRs).
// ---------------------------------------------------------------------------
__global__
__attribute__((amdgpu_flat_work_group_size(128, 128), amdgpu_waves_per_eu(2, 2)))
void lstm_kernel(const int* __restrict__ x,
                 const float* __restrict__ Uf, const float* __restrict__ Ub,
                 const float* __restrict__ zf_tab,
                 const float* __restrict__ zb_tab,
                 float* __restrict__ hcat)    // [BATCH][2*HID]
{
    const int tid = threadIdx.x;
    const int l   = tid & 63;          // lane = hidden unit
    const int w   = tid >> 6;          // 0: {i,f}, 1: {g,o}
    const int b   = blockIdx.x >> 1;
    const int d   = blockIdx.x & 1;

    const float* U    = d ? Ub : Uf;
    const float* ztab = d ? zb_tab : zf_tab;

    // owned columns: c0 = (2w)*64 + l, c1 = (2w+1)*64 + l
    float u0[HID], u1[HID];
#pragma unroll
    for (int k = 0; k < HID; ++k) u0[k] = U[k * NGATE + (2 * w) * 64 + l];
#pragma unroll
    for (int k = 0; k < HID; ++k) u1[k] = U[k * NGATE + (2 * w + 1) * 64 + l];

    __shared__ float zs[2][2][2][64];   // [buf][wave][which][unit]

    float hval = 0.0f;                  // lane l: h[l] (replicated per wave)
    float cval = 0.0f;

    const int* xrow = x + b * T;

    // token chunks: lane s holds token for step base+s
    auto tok_idx = [&](int s) -> int {
        s = s < (T - 1) ? s : (T - 1);
        return d ? (T - 1 - s) : s;
    };
    int tok_chunk      = xrow[tok_idx(l)];
    int tok_next_chunk = xrow[tok_idx(64 + l)];

    int tok = bcasti(tok_chunk, 0);
    const float2* zt2 = (const float2*)ztab;
    // thread's float2 slot within a row: l*2 + w (float2 units)
    float2 zcur = zt2[(size_t)tok * 128 + l * 2 + w];

    for (int s = 0; s < T; ++s) {
        // ---- prefetch step s+1 ----
        const int tnl = (s + 1) & 63;
        if (tnl == 0) {                       // entering a new chunk at s+1
            tok_chunk = tok_next_chunk;
            tok_next_chunk = xrow[tok_idx(s + 65 + l)];
        }
        const int tok1 = bcasti(tok_chunk, tnl);
        const float2 znext = zt2[(size_t)tok1 * 128 + l * 2 + w];

        // ---- z = zx + h . U (one broadcast feeds two FMAs) ----
        float z0 = zcur.x, z1 = zcur.y, z2 = 0.f, z3 = 0.f;
#pragma unroll
        for (int k = 0; k < HID; k += 2) {
            const float h0 = bcastf(hval, k);
            const float h1 = bcastf(hval, k + 1);
            z0 = fmaf(h0, u0[k],     z0);
            z1 = fmaf(h0, u1[k],     z1);
            z2 = fmaf(h1, u0[k + 1], z2);
            z3 = fmaf(h1, u1[k + 1], z3);
        }
        const float za = z0 + z2;   // gate 2w   (i or g)
        const float zb = z1 + z3;   // gate 2w+1 (f or o)

        // wave-uniform activation: wave1's first gate is g -> tanh
        const float a0 = w ? fast_tanh(za) : fast_sigmoid(za);
        const float a1 = fast_sigmoid(zb);

        float (*buf)[2][64] = zs[s & 1];
        buf[w][0][l] = a0;
        buf[w][1][l] = a1;
        __syncthreads();                      // the only barrier per step

        const float b0 = buf[1 - w][0][l];
        const float b1 = buf[1 - w][1][l];

        // wave0: a=(i,f) b=(g,o);  wave1: a=(g,o) b=(i,f)
        const float ig = w ? b0 : a0;
        const float fg = w ? b1 : a1;
        const float gg = w ? a0 : b0;
        const float og = w ? a1 : b1;

        const float cn = fmaf(fg, cval, ig * gg);
        const float hn = og * fast_tanh(cn);
        if (tok != 0) { cval = cn; hval = hn; }   // pad mask (uniform)

        tok  = tok1;
        zcur = znext;
        // double-buffered zs: rewrite of buf[s&1] happens only after barrier
        // s+1, which every wave reaches only after its reads above.
    }

    if (w == 0) hcat[b * (2 * HID) + d * HID + l] = hval;
}

// ---------------------------------------------------------------------------
// Tiny MLP head: out[b] = relu(hcat[b] @ W1 + b1) @ W2 + b2
// ---------------------------------------------------------------------------
__global__ void mlp_kernel(const float* __restrict__ hcat,
                           const float* __restrict__ W1, const float* __restrict__ b1,
                           const float* __restrict__ W2, const float* __restrict__ b2,
                           float* __restrict__ out)
{
    const int b = blockIdx.x;
    const int tid = threadIdx.x;  // 64 threads
    __shared__ float h1[32];
    const float* h = hcat + b * (2 * HID);
    if (tid < 32) {
        float acc = b1[tid];
#pragma unroll
        for (int k = 0; k < 2 * HID; ++k) acc += h[k] * W1[k * 32 + tid];
        h1[tid] = fmaxf(acc, 0.0f);
    }
    __syncthreads();
    if (tid == 0) {
        float acc = b2[0];
#pragma unroll
        for (int m = 0; m < 32; ++m) acc += h1[m] * W2[m];
        out[b] = acc;
    }
}

extern "C" void kernel_launch(void* const* d_in, const int* in_sizes, int n_in,
                              void* d_out, int out_size, void* d_ws, size_t ws_size,
                              hipStream_t stream)
{
    const int*   x   = (const int*)d_in[0];
    const float* emb = (const float*)d_in[1];
    const float* Wf  = (const float*)d_in[2];
    const float* Uf  = (const float*)d_in[3];
    const float* bf  = (const float*)d_in[4];
    const float* Wb  = (const float*)d_in[5];
    const float* Ub  = (const float*)d_in[6];
    const float* bb  = (const float*)d_in[7];
    const float* W1  = (const float*)d_in[8];
    const float* b1  = (const float*)d_in[9];
    const float* W2  = (const float*)d_in[10];
    const float* b2  = (const float*)d_in[11];
    float* out = (float*)d_out;

    // workspace layout: [zf_tab | zb_tab | hcat]
    float* zf_tab = (float*)d_ws;                               // 50001*256 f32
    float* zb_tab = zf_tab + (size_t)VOCABP1 * NGATE;           // 50001*256 f32
    float* hcat   = zb_tab + (size_t)VOCABP1 * NGATE;           // 512*128  f32

    zxtab_kernel<<<dim3(2048), dim3(256), 0, stream>>>(
        emb, Wf, bf, Wb, bb, zf_tab, zb_tab);
    lstm_kernel<<<dim3(2 * BATCH), dim3(128), 0, stream>>>(
        x, Uf, Ub, zf_tab, zb_tab, hcat);
    mlp_kernel<<<dim3(BATCH), dim3(64), 0, stream>>>(
        hcat, W1, b1, W2, b2, out);
}